// Round 9
// baseline (1103.083 us; speedup 1.0000x reference)
//
#include <hip/hip_runtime.h>
#include <cstdint>

// RGPR-GNN (GPR-GNN + RGCN basis-decomp convs) for MI355X.
// R9: FUSED aggregate+GEMM. The aggB[N,896] round-trip (87.5 MB write + ~64 MB
// HBM re-fetch per layer) is eliminated: the layer GEMM's K-loop phases are
// [self | rel0..rel6]; for rel phases the A-tile is BUILT IN LDS by gathering
// curA rows (12.8 MB, L2/LLC-hot) over the (dst,rel)-sorted edge segments,
// fp32 accum + mean + bf16. B-tile is LDS-staged (R8 lesson: strided per-lane
// B-fragment loads from global serialize on L2 latency). M-tile 64, grid 782,
// LDS 52 KB -> 3 blocks/CU. Fused epilogue: relu/temp/hidden RMW/curAout.
// Edge sort by (dst,rel) runs ONCE: hist -> 3-kernel scan over N*R -> placement.

constexpr int N_NODES  = 50000;
constexpr int E_EDGES  = 600000;
constexpr int R_REL    = 7;
constexpr int HID      = 128;
constexpr int IN_C     = 256;
constexpr int L_LAYERS = 3;
constexpr int K_CAT    = 1024;          // 128 self + 896 agg
constexpr int NR       = N_NODES * R_REL;            // 350000 segments
constexpr int SCANR_BLOCKS = (NR + 255) / 256;       // 1368

#define DEVI __device__ __forceinline__

using short8  = __attribute__((ext_vector_type(8))) short;
using floatx4 = __attribute__((ext_vector_type(4))) float;

DEVI unsigned short f2bf(float f) {
  unsigned u = __float_as_uint(f);
  unsigned r = (u + 0x7FFFu + ((u >> 16) & 1u)) >> 16;  // RNE
  return (unsigned short)r;
}
DEVI float bf2f(unsigned short h) { return __uint_as_float(((unsigned)h) << 16); }

// ---------------------------------------------------------------- prep casts
__global__ __launch_bounds__(256) void cast_x_kernel(
    const float* __restrict__ x, unsigned short* __restrict__ xbf)
{
  int i = blockIdx.x * 256 + threadIdx.x;      // over N*IN_C/4
  if (i >= N_NODES * IN_C / 4) return;
  float4 v = ((const float4*)x)[i];
  uint2 p;
  p.x = (unsigned)f2bf(v.x) | ((unsigned)f2bf(v.y) << 16);
  p.y = (unsigned)f2bf(v.z) | ((unsigned)f2bf(v.w) << 16);
  ((uint2*)xbf)[i] = p;
}

__global__ __launch_bounds__(256) void cast_w1_kernel(
    const float* __restrict__ w1, unsigned short* __restrict__ w1T)
{
  int t = blockIdx.x * 256 + threadIdx.x;      // 128*256
  if (t >= HID * IN_C) return;
  int m = t >> 8, k = t & 255;
  w1T[m * IN_C + k] = f2bf(w1[k * HID + m]);
}

// Wcat2T bf16: [L][f=128][k=1024]. k<128 -> roots[l][k][f]; k>=128 -> W[r][d][f]
__global__ __launch_bounds__(256) void build_wcat2(
    const float* __restrict__ comps,   // [L,R,8]
    const float* __restrict__ bases,   // [L,8,128,128]
    const float* __restrict__ roots,   // [L,128,128]
    unsigned short* __restrict__ wcat2T)
{
  int t = blockIdx.x * 256 + threadIdx.x;
  if (t >= L_LAYERS * 128 * K_CAT) return;
  int l   = t >> 17;
  int rem = t & 131071;
  int f   = rem >> 10;
  int k   = rem & 1023;
  float v;
  if (k < 128) {
    v = roots[((size_t)l * 128 + k) * 128 + f];
  } else {
    int r = (k - 128) >> 7, d = (k - 128) & 127;
    const float* cp = comps + ((size_t)l * R_REL + r) * 8;
    const float* bp = bases + (((size_t)l * 8) * 128 + d) * 128 + f;
    float s = 0.f;
#pragma unroll
    for (int b = 0; b < 8; ++b) s += cp[b] * bp[(size_t)b * 128 * 128];
    v = s;
  }
  wcat2T[t] = f2bf(v);
}

// ---------------------------------------------------------------- histogram (dst,rel)
__global__ __launch_bounds__(256) void hist_kernel(
    const int* __restrict__ ei, const int* __restrict__ et,
    int* __restrict__ cntRel)
{
  int e = blockIdx.x * 256 + threadIdx.x;
  if (e >= E_EDGES) return;
  atomicAdd(&cntRel[ei[E_EDGES + e] * R_REL + et[e]], 1);
}

// ---------------------------------------------------------------- scan over NR
__global__ __launch_bounds__(256) void scanA_kernel(
    const int* __restrict__ cnt, int* __restrict__ tmpOff,
    int* __restrict__ blockSums)
{
  __shared__ int s[256];
  int i = blockIdx.x * 256 + threadIdx.x;
  int v = (i < NR) ? cnt[i] : 0;
  s[threadIdx.x] = v;
  __syncthreads();
#pragma unroll
  for (int d = 1; d < 256; d <<= 1) {
    int t = (threadIdx.x >= d) ? s[threadIdx.x - d] : 0;
    __syncthreads();
    s[threadIdx.x] += t;
    __syncthreads();
  }
  if (i < NR) tmpOff[i] = s[threadIdx.x] - v;   // exclusive within block
  if (threadIdx.x == 255) blockSums[blockIdx.x] = s[255];
}

// single block, serial chunks with carry (SCANR_BLOCKS = 1368)
__global__ __launch_bounds__(256) void scanB_kernel(int* __restrict__ bs)
{
  __shared__ int s[256];
  __shared__ int carry;
  if (threadIdx.x == 0) carry = 0;
  __syncthreads();
  for (int base = 0; base < SCANR_BLOCKS; base += 256) {
    int cOld = carry;
    int i = base + threadIdx.x;
    int v = (i < SCANR_BLOCKS) ? bs[i] : 0;
    s[threadIdx.x] = v;
    __syncthreads();
#pragma unroll
    for (int d = 1; d < 256; d <<= 1) {
      int t = (threadIdx.x >= d) ? s[threadIdx.x - d] : 0;
      __syncthreads();
      s[threadIdx.x] += t;
      __syncthreads();
    }
    if (i < SCANR_BLOCKS) bs[i] = s[threadIdx.x] - v + cOld;  // exclusive
    __syncthreads();
    if (threadIdx.x == 0) carry = cOld + s[255];
    __syncthreads();
  }
}

__global__ __launch_bounds__(256) void scanC_kernel(
    const int* __restrict__ tmpOff, const int* __restrict__ blockSums,
    int* __restrict__ drs)
{
  int i = blockIdx.x * 256 + threadIdx.x;
  if (i < NR) drs[i] = tmpOff[i] + blockSums[blockIdx.x];
  if (i == 0) drs[NR] = E_EDGES;
}

// ---------------------------------------------------------------- placement
__global__ __launch_bounds__(256) void place_kernel(
    const int* __restrict__ ei, const int* __restrict__ et,
    const int* __restrict__ drs, int* __restrict__ cursor,
    unsigned short* __restrict__ esrc)
{
  int e = blockIdx.x * 256 + threadIdx.x;
  if (e >= E_EDGES) return;
  int seg = ei[E_EDGES + e] * R_REL + et[e];
  int pos = drs[seg] + atomicAdd(&cursor[seg], 1);
  esrc[pos] = (unsigned short)ei[e];   // src < 50000 < 65536
}

// ---------------------------------------------------------------- lin1 MFMA GEMM
// 128x128 tile, K=256: hidden = t0*(x@w1+b1) fp32, curA = bf16(same). grid(391).
__global__ __launch_bounds__(256) void gemm_lin1(
    const unsigned short* __restrict__ A,     // xbf [N,256]
    const unsigned short* __restrict__ BT,    // w1T [128,256]
    const float* __restrict__ bias,
    const float* __restrict__ temp,
    float* __restrict__ out0,                 // hidden fp32
    unsigned short* __restrict__ outT)        // curA bf16
{
  __shared__ unsigned short As[128][136];
  __shared__ unsigned short Bs[128][136];
  const int tid  = threadIdx.x;
  const int row0 = blockIdx.x * 128;
  const int lane = tid & 63;
  const int wid  = tid >> 6;
  const int wrow = (wid & 1) * 64;
  const int wcol = (wid >> 1) * 64;
  const int l15  = lane & 15;
  const int quad = lane >> 4;

  floatx4 acc[4][4] = {};

  for (int k0 = 0; k0 < IN_C; k0 += 128) {
#pragma unroll
    for (int it = 0; it < 8; ++it) {
      int chunk = it * 256 + tid;
      int r = chunk >> 4, cc = (chunk & 15) << 3;
      int grow = row0 + r;
      uint4 va = make_uint4(0u, 0u, 0u, 0u);
      if (grow < N_NODES)
        va = *(const uint4*)(A + (size_t)grow * IN_C + k0 + cc);
      *(uint4*)(&As[r][cc]) = va;
      *(uint4*)(&Bs[r][cc]) = *(const uint4*)(BT + (size_t)r * IN_C + k0 + cc);
    }
    __syncthreads();
#pragma unroll
    for (int ks = 0; ks < 4; ++ks) {
      int kc = ks * 32 + quad * 8;
      short8 af[4], bfr[4];
#pragma unroll
      for (int i = 0; i < 4; ++i)
        af[i] = *(const short8*)(&As[wrow + i * 16 + l15][kc]);
#pragma unroll
      for (int j = 0; j < 4; ++j)
        bfr[j] = *(const short8*)(&Bs[wcol + j * 16 + l15][kc]);
#pragma unroll
      for (int i = 0; i < 4; ++i)
#pragma unroll
        for (int j = 0; j < 4; ++j)
          acc[i][j] = __builtin_amdgcn_mfma_f32_16x16x32_bf16(
              af[i], bfr[j], acc[i][j], 0, 0, 0);
    }
    __syncthreads();
  }

  // C/D layout: col = lane&15, row = quad*4 + reg
  float t0 = temp[0];
#pragma unroll
  for (int i = 0; i < 4; ++i) {
    int lrow0 = wrow + i * 16 + quad * 4;
#pragma unroll
    for (int j = 0; j < 4; ++j) {
      int gcol = wcol + j * 16 + l15;
      float bb = bias[gcol];
#pragma unroll
      for (int r = 0; r < 4; ++r) {
        float v = t0 * (acc[i][j][r] + bb);
        int grow = row0 + lrow0 + r;
        if (grow < N_NODES) out0[(size_t)grow * HID + gcol] = v;
        As[lrow0 + r][gcol] = f2bf(v);
      }
    }
  }
  __syncthreads();
#pragma unroll
  for (int it = 0; it < 8; ++it) {
    int chunk = it * 256 + tid;
    int r = chunk >> 4, cc = (chunk & 15) << 3;
    int grow = row0 + r;
    if (grow < N_NODES)
      *(uint4*)(outT + (size_t)grow * HID + cc) = *(const uint4*)(&As[r][cc]);
  }
}

// ---------------------------------------------------------------- fused RGCN layer
// 64x128 output tile, grid(782). K-phases p=0..7: p=0 self (A-tile from curA),
// p>=1 rel r=p-1 (A-tile BUILT by gathering curA rows over (dst,rel) segments,
// fp32 accum -> mean -> bf16 -> LDS). B-tile (128x128 of wcat2T) LDS-staged per
// phase. Fused epilogue: c=(l<2?relu:id)(acc+bias); hidden += temp[l+1]*c;
// curAout=bf16(c).
__global__ __launch_bounds__(256) void rgcn_fused(
    const unsigned short* __restrict__ curA,   // [N,128] bf16 (in)
    const unsigned short* __restrict__ esrc,   // sorted by (dst,rel)
    const int* __restrict__ drs,               // [N*R+1] segment starts
    const unsigned short* __restrict__ BT,     // wcat2T layer slice [128][1024]
    const float* __restrict__ bias,
    const float* __restrict__ temp,
    float* __restrict__ hidden,                // fp32, read-modify-write
    unsigned short* __restrict__ curAout,      // [N,128] bf16 (out, l<2)
    int layer)
{
  __shared__ unsigned short Atile[64][136];    // 17.4 KB
  __shared__ unsigned short Btile[128][136];   // 34.8 KB
  const int tid  = threadIdx.x;
  const int row0 = blockIdx.x * 64;
  const int lane = tid & 63;
  const int wid  = tid >> 6;
  const int wrow = (wid & 1) * 32;
  const int wcol = (wid >> 1) * 64;
  const int l15  = lane & 15;
  const int quad = lane >> 4;
  const unsigned* curW = (const unsigned*)curA;   // 64 uints per node row

  floatx4 acc[2][4] = {};

  for (int p = 0; p < 8; ++p) {
    // stage B tile: rows n=0..127 (output cols), k slice [p*128, p*128+128)
#pragma unroll
    for (int it = 0; it < 8; ++it) {
      int chunk = it * 256 + tid;              // 2048 chunks of 8 shorts
      int n = chunk >> 4, cc = (chunk & 15) << 3;
      *(uint4*)(&Btile[n][cc]) =
          *(const uint4*)(BT + (size_t)n * K_CAT + p * 128 + cc);
    }
    if (p == 0) {
      // self phase: A tile straight from curA
#pragma unroll
      for (int it = 0; it < 4; ++it) {
        int chunk = it * 256 + tid;            // 1024 chunks
        int r = chunk >> 4, cc = (chunk & 15) << 3;
        int grow = row0 + r;
        uint4 va = make_uint4(0u, 0u, 0u, 0u);
        if (grow < N_NODES)
          va = *(const uint4*)(curA + (size_t)grow * HID + cc);
        *(uint4*)(&Atile[r][cc]) = va;
      }
    } else {
      // rel phase: wave w builds A rows [w*16, w*16+16) by segment gather
      const int rel = p - 1;
      for (int i = 0; i < 16; ++i) {
        int ld  = wid * 16 + i;
        int dst = row0 + ld;
        if (dst < N_NODES) {
          int seg = dst * R_REL + rel;
          int a = __builtin_amdgcn_readfirstlane(drs[seg]);
          int b = __builtin_amdgcn_readfirstlane(drs[seg + 1]);
          float sx = 0.f, sy = 0.f;
          for (int q = a; q < b; ++q) {
            unsigned v = curW[(size_t)((int)esrc[q]) * 64 + lane];
            sx += bf2f((unsigned short)(v & 0xFFFF));
            sy += bf2f((unsigned short)(v >> 16));
          }
          float sc = (b > a) ? 1.0f / (float)(b - a) : 0.f;
          unsigned pck =
              (unsigned)f2bf(sx * sc) | ((unsigned)f2bf(sy * sc) << 16);
          *(unsigned*)(&Atile[ld][lane * 2]) = pck;
        }
      }
    }
    __syncthreads();
#pragma unroll
    for (int ks = 0; ks < 4; ++ks) {
      int kc = ks * 32 + quad * 8;
      short8 af[2], bfr[4];
#pragma unroll
      for (int i = 0; i < 2; ++i)
        af[i] = *(const short8*)(&Atile[wrow + i * 16 + l15][kc]);
#pragma unroll
      for (int j = 0; j < 4; ++j)
        bfr[j] = *(const short8*)(&Btile[wcol + j * 16 + l15][kc]);
#pragma unroll
      for (int i = 0; i < 2; ++i)
#pragma unroll
        for (int j = 0; j < 4; ++j)
          acc[i][j] = __builtin_amdgcn_mfma_f32_16x16x32_bf16(
              af[i], bfr[j], acc[i][j], 0, 0, 0);
    }
    __syncthreads();
  }

  // fused epilogue. C/D layout: col = lane&15, row = quad*4 + reg
  const float tl = temp[layer + 1];
  const bool isLast = (layer == L_LAYERS - 1);
#pragma unroll
  for (int i = 0; i < 2; ++i) {
    int lrow0 = wrow + i * 16 + quad * 4;
#pragma unroll
    for (int j = 0; j < 4; ++j) {
      int gcol = wcol + j * 16 + l15;
      float bb = bias[gcol];
#pragma unroll
      for (int r = 0; r < 4; ++r) {
        int grow = row0 + lrow0 + r;
        float c = acc[i][j][r] + bb;
        if (!isLast) c = fmaxf(c, 0.f);
        if (grow < N_NODES) {
          float* hp = hidden + (size_t)grow * HID + gcol;
          *hp += tl * c;
        }
        Atile[lrow0 + r][gcol] = f2bf(c);
      }
    }
  }
  if (!isLast) {
    __syncthreads();
#pragma unroll
    for (int it = 0; it < 4; ++it) {
      int chunk = it * 256 + tid;
      int r = chunk >> 4, cc = (chunk & 15) << 3;
      int grow = row0 + r;
      if (grow < N_NODES)
        *(uint4*)(curAout + (size_t)grow * HID + cc) =
            *(const uint4*)(&Atile[r][cc]);
    }
  }
}

// ---------------------------------------------------------------- final linear
__global__ __launch_bounds__(256) void final_kernel(
    const float* __restrict__ hidden, const float* __restrict__ w2,
    const float* __restrict__ b2, float* __restrict__ out)
{
  int node = blockIdx.x * 4 + (threadIdx.x >> 6);
  int lane = threadIdx.x & 63;
  if (node >= N_NODES) return;
  float h0 = hidden[(size_t)node * HID + lane];
  float h1 = hidden[(size_t)node * HID + 64 + lane];
  float a0 = h0 * w2[lane * 2 + 0] + h1 * w2[(lane + 64) * 2 + 0];
  float a1 = h0 * w2[lane * 2 + 1] + h1 * w2[(lane + 64) * 2 + 1];
#pragma unroll
  for (int off = 32; off > 0; off >>= 1) {
    a0 += __shfl_down(a0, off);
    a1 += __shfl_down(a1, off);
  }
  if (lane == 0) {
    out[node * 2 + 0] = a0 + b2[0];
    out[node * 2 + 1] = a1 + b2[1];
  }
}

// ---------------------------------------------------------------- launcher
extern "C" void kernel_launch(void* const* d_in, const int* in_sizes, int n_in,
                              void* d_out, int out_size, void* d_ws, size_t ws_size,
                              hipStream_t stream) {
  const float* x     = (const float*)d_in[0];
  const int*   ei    = (const int*)d_in[1];
  const int*   et    = (const int*)d_in[2];
  const float* temp  = (const float*)d_in[3];
  const float* w1    = (const float*)d_in[4];
  const float* b1    = (const float*)d_in[5];
  const float* w2    = (const float*)d_in[6];
  const float* b2    = (const float*)d_in[7];
  const float* comps = (const float*)d_in[8];
  const float* bases = (const float*)d_in[9];
  const float* roots = (const float*)d_in[10];
  const float* cbias = (const float*)d_in[11];

  char* ws = (char*)d_ws;
  size_t off = 0;
  auto take = [&](size_t bytes) {
    char* p = ws + off;
    off = (off + bytes + 255) & ~(size_t)255;
    return p;
  };
  unsigned short* wcat2T = (unsigned short*)take((size_t)L_LAYERS * 128 * K_CAT * 2); // 0.8 MB
  unsigned short* xbf    = (unsigned short*)take((size_t)N_NODES * IN_C * 2);         // 25.6 MB
  unsigned short* w1T    = (unsigned short*)take((size_t)HID * IN_C * 2);             // 64 KB
  int*   cntRel  = (int*)take((size_t)NR * 4);                  // 1.4 MB
  int*   tmpOffR = (int*)take((size_t)NR * 4);                  // 1.4 MB
  int*   blockSumsR = (int*)take((size_t)SCANR_BLOCKS * 4);
  int*   drs     = (int*)take((size_t)(NR + 1) * 4);            // 1.4 MB
  int*   cursorR = (int*)take((size_t)NR * 4);                  // 1.4 MB
  unsigned short* esrc = (unsigned short*)take((size_t)E_EDGES * 2); // 1.2 MB
  float* hidden  = (float*)take((size_t)N_NODES * HID * 4);     // 25.6 MB
  unsigned short* curA  = (unsigned short*)take((size_t)N_NODES * HID * 2); // 12.8 MB
  unsigned short* curA2 = (unsigned short*)take((size_t)N_NODES * HID * 2); // 12.8 MB

  hipMemsetAsync(cntRel, 0, (size_t)NR * 4, stream);
  hipMemsetAsync(cursorR, 0, (size_t)NR * 4, stream);

  hipLaunchKernelGGL(build_wcat2, dim3((L_LAYERS * 128 * K_CAT + 255) / 256),
                     dim3(256), 0, stream, comps, bases, roots, wcat2T);
  hipLaunchKernelGGL(cast_x_kernel, dim3((N_NODES * IN_C / 4 + 255) / 256),
                     dim3(256), 0, stream, x, xbf);
  hipLaunchKernelGGL(cast_w1_kernel, dim3((HID * IN_C + 255) / 256), dim3(256),
                     0, stream, w1, w1T);
  hipLaunchKernelGGL(hist_kernel, dim3((E_EDGES + 255) / 256), dim3(256), 0,
                     stream, ei, et, cntRel);
  hipLaunchKernelGGL(scanA_kernel, dim3(SCANR_BLOCKS), dim3(256), 0, stream,
                     cntRel, tmpOffR, blockSumsR);
  hipLaunchKernelGGL(scanB_kernel, dim3(1), dim3(256), 0, stream, blockSumsR);
  hipLaunchKernelGGL(scanC_kernel, dim3(SCANR_BLOCKS), dim3(256), 0, stream,
                     tmpOffR, blockSumsR, drs);
  hipLaunchKernelGGL(place_kernel, dim3((E_EDGES + 255) / 256), dim3(256), 0,
                     stream, ei, et, drs, cursorR, esrc);

  const int rowBlocks   = (N_NODES + 127) / 128;   // 391
  const int rowBlocks64 = (N_NODES + 63) / 64;     // 782
  hipLaunchKernelGGL(gemm_lin1, dim3(rowBlocks), dim3(256), 0, stream,
                     xbf, w1T, b1, temp, hidden, curA);

  const unsigned short* cin = curA;
  unsigned short* cout = curA2;
  for (int l = 0; l < L_LAYERS; ++l) {
    hipLaunchKernelGGL(rgcn_fused, dim3(rowBlocks64), dim3(256), 0, stream,
                       cin, esrc, drs, wcat2T + (size_t)l * 128 * K_CAT,
                       cbias + (size_t)l * HID, temp, hidden, cout, l);
    const unsigned short* t = cin; cin = cout; cout = (unsigned short*)t;
  }

  hipLaunchKernelGGL(final_kernel, dim3((N_NODES + 3) / 4), dim3(256), 0, stream,
                     hidden, w2, b2, (float*)d_out);
}

// Round 10
// 587.657 us; speedup vs baseline: 1.8771x; 1.8771x over previous
//
#include <hip/hip_runtime.h>
#include <cstdint>

// RGPR-GNN (GPR-GNN + RGCN basis-decomp convs) for MI355X.
// R10: R7 structure (best known: standalone latency-tolerant agg + separate
// MFMA GEMM) with gemm_layer re-tiled M=64 (grid 782) and B LDS-STAGED
// (R8 lesson: direct per-lane B loads serialize on L2 latency; R9 lesson:
// gather must not live inside a barriered MFMA K-loop). LDS 52.2 KB -> 3
// blocks/CU (vs R7's 68 KB -> 2).
// Per layer:
//   agg_reg:   one wave per dst, (dst,rel)-sorted edges, register accum.
//   gemm_layer: curB=[curA|agg](K=1024)@Wcat2 + bias, FUSED epilogue:
//              c=(l<2?relu:id)(.); hidden += temp[l+1]*c; curAout=bf16(c).
// Edge sort by (dst,rel) runs ONCE: hist -> 3-kernel scan over N*R -> placement.

constexpr int N_NODES  = 50000;
constexpr int E_EDGES  = 600000;
constexpr int R_REL    = 7;
constexpr int HID      = 128;
constexpr int IN_C     = 256;
constexpr int L_LAYERS = 3;
constexpr int AGG_COLS = 896;           // 7*128 aggregated message columns
constexpr int K_CAT    = 1024;          // 128 self + 896 agg
constexpr int NR       = N_NODES * R_REL;            // 350000 segments
constexpr int SCANR_BLOCKS = (NR + 255) / 256;       // 1368

#define DEVI __device__ __forceinline__

using short8  = __attribute__((ext_vector_type(8))) short;
using floatx4 = __attribute__((ext_vector_type(4))) float;

DEVI unsigned short f2bf(float f) {
  unsigned u = __float_as_uint(f);
  unsigned r = (u + 0x7FFFu + ((u >> 16) & 1u)) >> 16;  // RNE
  return (unsigned short)r;
}
DEVI float bf2f(unsigned short h) { return __uint_as_float(((unsigned)h) << 16); }

// ---------------------------------------------------------------- prep casts
__global__ __launch_bounds__(256) void cast_x_kernel(
    const float* __restrict__ x, unsigned short* __restrict__ xbf)
{
  int i = blockIdx.x * 256 + threadIdx.x;      // over N*IN_C/4
  if (i >= N_NODES * IN_C / 4) return;
  float4 v = ((const float4*)x)[i];
  uint2 p;
  p.x = (unsigned)f2bf(v.x) | ((unsigned)f2bf(v.y) << 16);
  p.y = (unsigned)f2bf(v.z) | ((unsigned)f2bf(v.w) << 16);
  ((uint2*)xbf)[i] = p;
}

__global__ __launch_bounds__(256) void cast_w1_kernel(
    const float* __restrict__ w1, unsigned short* __restrict__ w1T)
{
  int t = blockIdx.x * 256 + threadIdx.x;      // 128*256
  if (t >= HID * IN_C) return;
  int m = t >> 8, k = t & 255;
  w1T[m * IN_C + k] = f2bf(w1[k * HID + m]);
}

// Wcat2T bf16: [L][f=128][k=1024]. k<128 -> roots[l][k][f]; k>=128 -> W[r][d][f]
__global__ __launch_bounds__(256) void build_wcat2(
    const float* __restrict__ comps,   // [L,R,8]
    const float* __restrict__ bases,   // [L,8,128,128]
    const float* __restrict__ roots,   // [L,128,128]
    unsigned short* __restrict__ wcat2T)
{
  int t = blockIdx.x * 256 + threadIdx.x;
  if (t >= L_LAYERS * 128 * K_CAT) return;
  int l   = t >> 17;
  int rem = t & 131071;
  int f   = rem >> 10;
  int k   = rem & 1023;
  float v;
  if (k < 128) {
    v = roots[((size_t)l * 128 + k) * 128 + f];
  } else {
    int r = (k - 128) >> 7, d = (k - 128) & 127;
    const float* cp = comps + ((size_t)l * R_REL + r) * 8;
    const float* bp = bases + (((size_t)l * 8) * 128 + d) * 128 + f;
    float s = 0.f;
#pragma unroll
    for (int b = 0; b < 8; ++b) s += cp[b] * bp[(size_t)b * 128 * 128];
    v = s;
  }
  wcat2T[t] = f2bf(v);
}

// ---------------------------------------------------------------- histogram (dst,rel)
__global__ __launch_bounds__(256) void hist_kernel(
    const int* __restrict__ ei, const int* __restrict__ et,
    int* __restrict__ cntRel)
{
  int e = blockIdx.x * 256 + threadIdx.x;
  if (e >= E_EDGES) return;
  atomicAdd(&cntRel[ei[E_EDGES + e] * R_REL + et[e]], 1);
}

// ---------------------------------------------------------------- scan over NR
__global__ __launch_bounds__(256) void scanA_kernel(
    const int* __restrict__ cnt, int* __restrict__ tmpOff,
    int* __restrict__ blockSums)
{
  __shared__ int s[256];
  int i = blockIdx.x * 256 + threadIdx.x;
  int v = (i < NR) ? cnt[i] : 0;
  s[threadIdx.x] = v;
  __syncthreads();
#pragma unroll
  for (int d = 1; d < 256; d <<= 1) {
    int t = (threadIdx.x >= d) ? s[threadIdx.x - d] : 0;
    __syncthreads();
    s[threadIdx.x] += t;
    __syncthreads();
  }
  if (i < NR) tmpOff[i] = s[threadIdx.x] - v;   // exclusive within block
  if (threadIdx.x == 255) blockSums[blockIdx.x] = s[255];
}

// single block, serial chunks with carry (SCANR_BLOCKS = 1368)
__global__ __launch_bounds__(256) void scanB_kernel(int* __restrict__ bs)
{
  __shared__ int s[256];
  __shared__ int carry;
  if (threadIdx.x == 0) carry = 0;
  __syncthreads();
  for (int base = 0; base < SCANR_BLOCKS; base += 256) {
    int cOld = carry;
    int i = base + threadIdx.x;
    int v = (i < SCANR_BLOCKS) ? bs[i] : 0;
    s[threadIdx.x] = v;
    __syncthreads();
#pragma unroll
    for (int d = 1; d < 256; d <<= 1) {
      int t = (threadIdx.x >= d) ? s[threadIdx.x - d] : 0;
      __syncthreads();
      s[threadIdx.x] += t;
      __syncthreads();
    }
    if (i < SCANR_BLOCKS) bs[i] = s[threadIdx.x] - v + cOld;  // exclusive
    __syncthreads();
    if (threadIdx.x == 0) carry = cOld + s[255];
    __syncthreads();
  }
}

__global__ __launch_bounds__(256) void scanC_kernel(
    const int* __restrict__ tmpOff, const int* __restrict__ blockSums,
    int* __restrict__ drs)
{
  int i = blockIdx.x * 256 + threadIdx.x;
  if (i < NR) drs[i] = tmpOff[i] + blockSums[blockIdx.x];
  if (i == 0) drs[NR] = E_EDGES;
}

// ---------------------------------------------------------------- placement
__global__ __launch_bounds__(256) void place_kernel(
    const int* __restrict__ ei, const int* __restrict__ et,
    const int* __restrict__ drs, int* __restrict__ cursor,
    unsigned short* __restrict__ esrc)
{
  int e = blockIdx.x * 256 + threadIdx.x;
  if (e >= E_EDGES) return;
  int seg = ei[E_EDGES + e] * R_REL + et[e];
  int pos = drs[seg] + atomicAdd(&cursor[seg], 1);
  esrc[pos] = (unsigned short)ei[e];   // src < 50000 < 65536
}

// ---------------------------------------------------------------- aggregation
// One wave per dst; 64 lanes x 2 dims = full 256B curA row per edge (coalesced).
// Edges sorted (dst,rel): per-relation float2 REGISTER accum; mean = 1/(b-a).
__global__ __launch_bounds__(256) void agg_reg_kernel(
    const unsigned short* __restrict__ curA,   // [N,128] bf16
    const unsigned short* __restrict__ esrc,   // sorted by (dst,rel)
    const int* __restrict__ drs,               // [N*R+1] segment starts
    unsigned short* __restrict__ aggB)         // [N,896] bf16
{
  const int tid  = threadIdx.x;
  const int lane = tid & 63;
  const int dst  = blockIdx.x * 4 + (tid >> 6);
  if (dst >= N_NODES) return;
  const int segBase = dst * R_REL;

  int bnd = drs[segBase + (lane & 7)];
  const int a0    = __shfl(bnd, 0);
  const int total = __shfl(bnd, 7) - a0;

  int pk = 0;
  if (lane < total) pk = (int)esrc[a0 + lane];   // covers total<=64 (deg avg 12)

  const unsigned* colp = (const unsigned*)curA + lane;   // row stride = 64 uints

  int p = a0;
  int aPrev = a0;
#pragma unroll
  for (int r = 0; r < R_REL; ++r) {
    int br = __shfl(bnd, r + 1);
    float sx = 0.f, sy = 0.f;
    for (; p < br; ++p) {
      int idx = p - a0;
      int src = (idx < 64) ? __shfl(pk, idx) : (int)esrc[p];  // rare tail path
      unsigned v = colp[src * 64];
      sx += bf2f((unsigned short)(v & 0xFFFF));
      sy += bf2f((unsigned short)(v >> 16));
    }
    int c = br - aPrev;
    float sc = (c > 0) ? 1.0f / (float)c : 0.f;
    unsigned pck = (unsigned)f2bf(sx * sc) | ((unsigned)f2bf(sy * sc) << 16);
    *(unsigned*)(aggB + (size_t)dst * AGG_COLS + r * HID + lane * 2) = pck;
    aPrev = br;
  }
}

// ---------------------------------------------------------------- lin1 MFMA GEMM
// 128x128 tile, K=256: hidden = t0*(x@w1+b1) fp32, curA = bf16(same). grid(391).
__global__ __launch_bounds__(256) void gemm_lin1(
    const unsigned short* __restrict__ A,     // xbf [N,256]
    const unsigned short* __restrict__ BT,    // w1T [128,256]
    const float* __restrict__ bias,
    const float* __restrict__ temp,
    float* __restrict__ out0,                 // hidden fp32
    unsigned short* __restrict__ outT)        // curA bf16
{
  __shared__ unsigned short As[128][136];
  __shared__ unsigned short Bs[128][136];
  const int tid  = threadIdx.x;
  const int row0 = blockIdx.x * 128;
  const int lane = tid & 63;
  const int wid  = tid >> 6;
  const int wrow = (wid & 1) * 64;
  const int wcol = (wid >> 1) * 64;
  const int l15  = lane & 15;
  const int quad = lane >> 4;

  floatx4 acc[4][4] = {};

  for (int k0 = 0; k0 < IN_C; k0 += 128) {
#pragma unroll
    for (int it = 0; it < 8; ++it) {
      int chunk = it * 256 + tid;
      int r = chunk >> 4, cc = (chunk & 15) << 3;
      int grow = row0 + r;
      uint4 va = make_uint4(0u, 0u, 0u, 0u);
      if (grow < N_NODES)
        va = *(const uint4*)(A + (size_t)grow * IN_C + k0 + cc);
      *(uint4*)(&As[r][cc]) = va;
      *(uint4*)(&Bs[r][cc]) = *(const uint4*)(BT + (size_t)r * IN_C + k0 + cc);
    }
    __syncthreads();
#pragma unroll
    for (int ks = 0; ks < 4; ++ks) {
      int kc = ks * 32 + quad * 8;
      short8 af[4], bfr[4];
#pragma unroll
      for (int i = 0; i < 4; ++i)
        af[i] = *(const short8*)(&As[wrow + i * 16 + l15][kc]);
#pragma unroll
      for (int j = 0; j < 4; ++j)
        bfr[j] = *(const short8*)(&Bs[wcol + j * 16 + l15][kc]);
#pragma unroll
      for (int i = 0; i < 4; ++i)
#pragma unroll
        for (int j = 0; j < 4; ++j)
          acc[i][j] = __builtin_amdgcn_mfma_f32_16x16x32_bf16(
              af[i], bfr[j], acc[i][j], 0, 0, 0);
    }
    __syncthreads();
  }

  // C/D layout: col = lane&15, row = quad*4 + reg
  float t0 = temp[0];
#pragma unroll
  for (int i = 0; i < 4; ++i) {
    int lrow0 = wrow + i * 16 + quad * 4;
#pragma unroll
    for (int j = 0; j < 4; ++j) {
      int gcol = wcol + j * 16 + l15;
      float bb = bias[gcol];
#pragma unroll
      for (int r = 0; r < 4; ++r) {
        float v = t0 * (acc[i][j][r] + bb);
        int grow = row0 + lrow0 + r;
        if (grow < N_NODES) out0[(size_t)grow * HID + gcol] = v;
        As[lrow0 + r][gcol] = f2bf(v);
      }
    }
  }
  __syncthreads();
#pragma unroll
  for (int it = 0; it < 8; ++it) {
    int chunk = it * 256 + tid;
    int r = chunk >> 4, cc = (chunk & 15) << 3;
    int grow = row0 + r;
    if (grow < N_NODES)
      *(uint4*)(outT + (size_t)grow * HID + cc) = *(const uint4*)(&As[r][cc]);
  }
}

// ---------------------------------------------------------------- layer MFMA GEMM
// 64x128 tile (grid 782), 4 waves of 32x64 (acc 2x4). A (17.4 KB) AND B
// (34.8 KB) LDS-staged -> 52.2 KB, 3 blocks/CU. FUSED epilogue:
//   c = (l<2 ? relu : id)(acc+bias); hidden += temp[l+1]*c; curAout = bf16(c)
__global__ __launch_bounds__(256) void gemm_layer(
    const unsigned short* __restrict__ curA,   // [N,128] bf16 (in)
    const unsigned short* __restrict__ aggB,   // [N,896] bf16
    const unsigned short* __restrict__ BT,     // wcat2T [128][1024] bf16
    const float* __restrict__ bias,
    const float* __restrict__ temp,
    float* __restrict__ hidden,                // fp32, read-modify-write
    unsigned short* __restrict__ curAout,      // [N,128] bf16 (out, l<2)
    int layer)
{
  __shared__ unsigned short Atile[64][136];    // 17.4 KB
  __shared__ unsigned short Btile[128][136];   // 34.8 KB
  const int tid  = threadIdx.x;
  const int row0 = blockIdx.x * 64;
  const int lane = tid & 63;
  const int wid  = tid >> 6;
  const int wrow = (wid & 1) * 32;
  const int wcol = (wid >> 1) * 64;
  const int l15  = lane & 15;
  const int quad = lane >> 4;

  floatx4 acc[2][4] = {};

  for (int p = 0; p < 8; ++p) {
    // stage B tile: rows n=0..127 (output cols), k slice [p*128, p*128+128)
#pragma unroll
    for (int it = 0; it < 8; ++it) {
      int chunk = it * 256 + tid;              // 2048 chunks of 8 shorts
      int n = chunk >> 4, cc = (chunk & 15) << 3;
      *(uint4*)(&Btile[n][cc]) =
          *(const uint4*)(BT + (size_t)n * K_CAT + p * 128 + cc);
    }
    // stage A tile: 64 rows x 128 k
#pragma unroll
    for (int it = 0; it < 4; ++it) {
      int chunk = it * 256 + tid;              // 1024 chunks
      int r = chunk >> 4, cc = (chunk & 15) << 3;
      int grow = row0 + r;
      uint4 va = make_uint4(0u, 0u, 0u, 0u);
      if (grow < N_NODES) {
        if (p == 0)
          va = *(const uint4*)(curA + (size_t)grow * HID + cc);
        else
          va = *(const uint4*)(aggB + (size_t)grow * AGG_COLS +
                               (p - 1) * 128 + cc);
      }
      *(uint4*)(&Atile[r][cc]) = va;
    }
    __syncthreads();
#pragma unroll
    for (int ks = 0; ks < 4; ++ks) {
      int kc = ks * 32 + quad * 8;
      short8 af[2], bfr[4];
#pragma unroll
      for (int i = 0; i < 2; ++i)
        af[i] = *(const short8*)(&Atile[wrow + i * 16 + l15][kc]);
#pragma unroll
      for (int j = 0; j < 4; ++j)
        bfr[j] = *(const short8*)(&Btile[wcol + j * 16 + l15][kc]);
#pragma unroll
      for (int i = 0; i < 2; ++i)
#pragma unroll
        for (int j = 0; j < 4; ++j)
          acc[i][j] = __builtin_amdgcn_mfma_f32_16x16x32_bf16(
              af[i], bfr[j], acc[i][j], 0, 0, 0);
    }
    __syncthreads();
  }

  // fused epilogue. C/D layout: col = lane&15, row = quad*4 + reg
  const float tl = temp[layer + 1];
  const bool isLast = (layer == L_LAYERS - 1);
#pragma unroll
  for (int i = 0; i < 2; ++i) {
    int lrow0 = wrow + i * 16 + quad * 4;
#pragma unroll
    for (int j = 0; j < 4; ++j) {
      int gcol = wcol + j * 16 + l15;
      float bb = bias[gcol];
#pragma unroll
      for (int r = 0; r < 4; ++r) {
        int grow = row0 + lrow0 + r;
        float c = acc[i][j][r] + bb;
        if (!isLast) c = fmaxf(c, 0.f);
        if (grow < N_NODES) {
          float* hp = hidden + (size_t)grow * HID + gcol;
          *hp += tl * c;
        }
        Atile[lrow0 + r][gcol] = f2bf(c);
      }
    }
  }
  if (!isLast) {
    __syncthreads();
#pragma unroll
    for (int it = 0; it < 4; ++it) {
      int chunk = it * 256 + tid;
      int r = chunk >> 4, cc = (chunk & 15) << 3;
      int grow = row0 + r;
      if (grow < N_NODES)
        *(uint4*)(curAout + (size_t)grow * HID + cc) =
            *(const uint4*)(&Atile[r][cc]);
    }
  }
}

// ---------------------------------------------------------------- final linear
__global__ __launch_bounds__(256) void final_kernel(
    const float* __restrict__ hidden, const float* __restrict__ w2,
    const float* __restrict__ b2, float* __restrict__ out)
{
  int node = blockIdx.x * 4 + (threadIdx.x >> 6);
  int lane = threadIdx.x & 63;
  if (node >= N_NODES) return;
  float h0 = hidden[(size_t)node * HID + lane];
  float h1 = hidden[(size_t)node * HID + 64 + lane];
  float a0 = h0 * w2[lane * 2 + 0] + h1 * w2[(lane + 64) * 2 + 0];
  float a1 = h0 * w2[lane * 2 + 1] + h1 * w2[(lane + 64) * 2 + 1];
#pragma unroll
  for (int off = 32; off > 0; off >>= 1) {
    a0 += __shfl_down(a0, off);
    a1 += __shfl_down(a1, off);
  }
  if (lane == 0) {
    out[node * 2 + 0] = a0 + b2[0];
    out[node * 2 + 1] = a1 + b2[1];
  }
}

// ---------------------------------------------------------------- launcher
extern "C" void kernel_launch(void* const* d_in, const int* in_sizes, int n_in,
                              void* d_out, int out_size, void* d_ws, size_t ws_size,
                              hipStream_t stream) {
  const float* x     = (const float*)d_in[0];
  const int*   ei    = (const int*)d_in[1];
  const int*   et    = (const int*)d_in[2];
  const float* temp  = (const float*)d_in[3];
  const float* w1    = (const float*)d_in[4];
  const float* b1    = (const float*)d_in[5];
  const float* w2    = (const float*)d_in[6];
  const float* b2    = (const float*)d_in[7];
  const float* comps = (const float*)d_in[8];
  const float* bases = (const float*)d_in[9];
  const float* roots = (const float*)d_in[10];
  const float* cbias = (const float*)d_in[11];

  char* ws = (char*)d_ws;
  size_t off = 0;
  auto take = [&](size_t bytes) {
    char* p = ws + off;
    off = (off + bytes + 255) & ~(size_t)255;
    return p;
  };
  unsigned short* wcat2T = (unsigned short*)take((size_t)L_LAYERS * 128 * K_CAT * 2); // 0.8 MB
  unsigned short* xbf    = (unsigned short*)take((size_t)N_NODES * IN_C * 2);         // 25.6 MB
  unsigned short* w1T    = (unsigned short*)take((size_t)HID * IN_C * 2);             // 64 KB
  int*   cntRel  = (int*)take((size_t)NR * 4);                  // 1.4 MB
  int*   tmpOffR = (int*)take((size_t)NR * 4);                  // 1.4 MB
  int*   blockSumsR = (int*)take((size_t)SCANR_BLOCKS * 4);
  int*   drs     = (int*)take((size_t)(NR + 1) * 4);            // 1.4 MB
  int*   cursorR = (int*)take((size_t)NR * 4);                  // 1.4 MB
  unsigned short* esrc = (unsigned short*)take((size_t)E_EDGES * 2); // 1.2 MB
  float* hidden  = (float*)take((size_t)N_NODES * HID * 4);     // 25.6 MB
  unsigned short* curA  = (unsigned short*)take((size_t)N_NODES * HID * 2); // 12.8 MB
  unsigned short* curA2 = (unsigned short*)take((size_t)N_NODES * HID * 2); // 12.8 MB
  unsigned short* aggB  = (unsigned short*)take((size_t)N_NODES * AGG_COLS * 2); // 89.6 MB

  hipMemsetAsync(cntRel, 0, (size_t)NR * 4, stream);
  hipMemsetAsync(cursorR, 0, (size_t)NR * 4, stream);

  hipLaunchKernelGGL(build_wcat2, dim3((L_LAYERS * 128 * K_CAT + 255) / 256),
                     dim3(256), 0, stream, comps, bases, roots, wcat2T);
  hipLaunchKernelGGL(cast_x_kernel, dim3((N_NODES * IN_C / 4 + 255) / 256),
                     dim3(256), 0, stream, x, xbf);
  hipLaunchKernelGGL(cast_w1_kernel, dim3((HID * IN_C + 255) / 256), dim3(256),
                     0, stream, w1, w1T);
  hipLaunchKernelGGL(hist_kernel, dim3((E_EDGES + 255) / 256), dim3(256), 0,
                     stream, ei, et, cntRel);
  hipLaunchKernelGGL(scanA_kernel, dim3(SCANR_BLOCKS), dim3(256), 0, stream,
                     cntRel, tmpOffR, blockSumsR);
  hipLaunchKernelGGL(scanB_kernel, dim3(1), dim3(256), 0, stream, blockSumsR);
  hipLaunchKernelGGL(scanC_kernel, dim3(SCANR_BLOCKS), dim3(256), 0, stream,
                     tmpOffR, blockSumsR, drs);
  hipLaunchKernelGGL(place_kernel, dim3((E_EDGES + 255) / 256), dim3(256), 0,
                     stream, ei, et, drs, cursorR, esrc);

  const int rowBlocks   = (N_NODES + 127) / 128;   // 391
  const int rowBlocks64 = (N_NODES + 63) / 64;     // 782
  hipLaunchKernelGGL(gemm_lin1, dim3(rowBlocks), dim3(256), 0, stream,
                     xbf, w1T, b1, temp, hidden, curA);

  const unsigned short* cin = curA;
  unsigned short* cout = curA2;
  for (int l = 0; l < L_LAYERS; ++l) {
    hipLaunchKernelGGL(agg_reg_kernel, dim3((N_NODES + 3) / 4), dim3(256),
                       0, stream, cin, esrc, drs, aggB);
    hipLaunchKernelGGL(gemm_layer, dim3(rowBlocks64), dim3(256), 0, stream,
                       cin, aggB, wcat2T + (size_t)l * 128 * K_CAT,
                       cbias + (size_t)l * HID, temp, hidden, cout, l);
    const unsigned short* t = cin; cin = cout; cout = (unsigned short*)t;
  }

  hipLaunchKernelGGL(final_kernel, dim3((N_NODES + 3) / 4), dim3(256), 0, stream,
                     hidden, w2, b2, (float*)d_out);
}

// Round 11
// 527.558 us; speedup vs baseline: 2.0909x; 1.1139x over previous
//
#include <hip/hip_runtime.h>
#include <cstdint>

// RGPR-GNN (GPR-GNN + RGCN basis-decomp convs) for MI355X.
// R11: traffic cuts on the R10 structure.
//  - NO fp32 hidden: layer epilogues write only bf16 c_l (b1..b3); final kernel
//    computes h = b0 + t1*b1 + t2*b2 + t3*b3 on the fly (b1/b2 double as the
//    next layer's input -> zero extra intermediates). Saves 51.2 MB RMW/layer.
//  - cast_x folded into lin1's LDS staging (xbf eliminated, -77 MB).
//  - gemm_layer M=32 tile (grid 1563, LDS 43.5 KB) for pipelining/tail.
// Per layer:
//   agg_reg:   one wave per dst, (dst,rel)-sorted edges, register accum.
//   gemm_layer: c=[curA|agg](K=1024)@Wcat2+bias, (relu if l<2), write bf16 only.
// Edge sort by (dst,rel) runs ONCE: hist -> 3-kernel scan over N*R -> placement.

constexpr int N_NODES  = 50000;
constexpr int E_EDGES  = 600000;
constexpr int R_REL    = 7;
constexpr int HID      = 128;
constexpr int IN_C     = 256;
constexpr int L_LAYERS = 3;
constexpr int AGG_COLS = 896;           // 7*128 aggregated message columns
constexpr int K_CAT    = 1024;          // 128 self + 896 agg
constexpr int NR       = N_NODES * R_REL;            // 350000 segments
constexpr int SCANR_BLOCKS = (NR + 255) / 256;       // 1368

#define DEVI __device__ __forceinline__

using short8  = __attribute__((ext_vector_type(8))) short;
using floatx4 = __attribute__((ext_vector_type(4))) float;

DEVI unsigned short f2bf(float f) {
  unsigned u = __float_as_uint(f);
  unsigned r = (u + 0x7FFFu + ((u >> 16) & 1u)) >> 16;  // RNE
  return (unsigned short)r;
}
DEVI float bf2f(unsigned short h) { return __uint_as_float(((unsigned)h) << 16); }

// ---------------------------------------------------------------- prep casts
__global__ __launch_bounds__(256) void cast_w1_kernel(
    const float* __restrict__ w1, unsigned short* __restrict__ w1T)
{
  int t = blockIdx.x * 256 + threadIdx.x;      // 128*256
  if (t >= HID * IN_C) return;
  int m = t >> 8, k = t & 255;
  w1T[m * IN_C + k] = f2bf(w1[k * HID + m]);
}

// Wcat2T bf16: [L][f=128][k=1024]. k<128 -> roots[l][k][f]; k>=128 -> W[r][d][f]
__global__ __launch_bounds__(256) void build_wcat2(
    const float* __restrict__ comps,   // [L,R,8]
    const float* __restrict__ bases,   // [L,8,128,128]
    const float* __restrict__ roots,   // [L,128,128]
    unsigned short* __restrict__ wcat2T)
{
  int t = blockIdx.x * 256 + threadIdx.x;
  if (t >= L_LAYERS * 128 * K_CAT) return;
  int l   = t >> 17;
  int rem = t & 131071;
  int f   = rem >> 10;
  int k   = rem & 1023;
  float v;
  if (k < 128) {
    v = roots[((size_t)l * 128 + k) * 128 + f];
  } else {
    int r = (k - 128) >> 7, d = (k - 128) & 127;
    const float* cp = comps + ((size_t)l * R_REL + r) * 8;
    const float* bp = bases + (((size_t)l * 8) * 128 + d) * 128 + f;
    float s = 0.f;
#pragma unroll
    for (int b = 0; b < 8; ++b) s += cp[b] * bp[(size_t)b * 128 * 128];
    v = s;
  }
  wcat2T[t] = f2bf(v);
}

// ---------------------------------------------------------------- histogram (dst,rel)
__global__ __launch_bounds__(256) void hist_kernel(
    const int* __restrict__ ei, const int* __restrict__ et,
    int* __restrict__ cntRel)
{
  int e = blockIdx.x * 256 + threadIdx.x;
  if (e >= E_EDGES) return;
  atomicAdd(&cntRel[ei[E_EDGES + e] * R_REL + et[e]], 1);
}

// ---------------------------------------------------------------- scan over NR
__global__ __launch_bounds__(256) void scanA_kernel(
    const int* __restrict__ cnt, int* __restrict__ tmpOff,
    int* __restrict__ blockSums)
{
  __shared__ int s[256];
  int i = blockIdx.x * 256 + threadIdx.x;
  int v = (i < NR) ? cnt[i] : 0;
  s[threadIdx.x] = v;
  __syncthreads();
#pragma unroll
  for (int d = 1; d < 256; d <<= 1) {
    int t = (threadIdx.x >= d) ? s[threadIdx.x - d] : 0;
    __syncthreads();
    s[threadIdx.x] += t;
    __syncthreads();
  }
  if (i < NR) tmpOff[i] = s[threadIdx.x] - v;   // exclusive within block
  if (threadIdx.x == 255) blockSums[blockIdx.x] = s[255];
}

// single block, serial chunks with carry (SCANR_BLOCKS = 1368)
__global__ __launch_bounds__(256) void scanB_kernel(int* __restrict__ bs)
{
  __shared__ int s[256];
  __shared__ int carry;
  if (threadIdx.x == 0) carry = 0;
  __syncthreads();
  for (int base = 0; base < SCANR_BLOCKS; base += 256) {
    int cOld = carry;
    int i = base + threadIdx.x;
    int v = (i < SCANR_BLOCKS) ? bs[i] : 0;
    s[threadIdx.x] = v;
    __syncthreads();
#pragma unroll
    for (int d = 1; d < 256; d <<= 1) {
      int t = (threadIdx.x >= d) ? s[threadIdx.x - d] : 0;
      __syncthreads();
      s[threadIdx.x] += t;
      __syncthreads();
    }
    if (i < SCANR_BLOCKS) bs[i] = s[threadIdx.x] - v + cOld;  // exclusive
    __syncthreads();
    if (threadIdx.x == 0) carry = cOld + s[255];
    __syncthreads();
  }
}

__global__ __launch_bounds__(256) void scanC_kernel(
    const int* __restrict__ tmpOff, const int* __restrict__ blockSums,
    int* __restrict__ drs)
{
  int i = blockIdx.x * 256 + threadIdx.x;
  if (i < NR) drs[i] = tmpOff[i] + blockSums[blockIdx.x];
  if (i == 0) drs[NR] = E_EDGES;
}

// ---------------------------------------------------------------- placement
__global__ __launch_bounds__(256) void place_kernel(
    const int* __restrict__ ei, const int* __restrict__ et,
    const int* __restrict__ drs, int* __restrict__ cursor,
    unsigned short* __restrict__ esrc)
{
  int e = blockIdx.x * 256 + threadIdx.x;
  if (e >= E_EDGES) return;
  int seg = ei[E_EDGES + e] * R_REL + et[e];
  int pos = drs[seg] + atomicAdd(&cursor[seg], 1);
  esrc[pos] = (unsigned short)ei[e];   // src < 50000 < 65536
}

// ---------------------------------------------------------------- aggregation
// One wave per dst; 64 lanes x 2 dims = full 256B curA row per edge (coalesced).
// Edges sorted (dst,rel): per-relation float2 REGISTER accum; mean = 1/(b-a).
__global__ __launch_bounds__(256) void agg_reg_kernel(
    const unsigned short* __restrict__ curA,   // [N,128] bf16
    const unsigned short* __restrict__ esrc,   // sorted by (dst,rel)
    const int* __restrict__ drs,               // [N*R+1] segment starts
    unsigned short* __restrict__ aggB)         // [N,896] bf16
{
  const int tid  = threadIdx.x;
  const int lane = tid & 63;
  const int dst  = blockIdx.x * 4 + (tid >> 6);
  if (dst >= N_NODES) return;
  const int segBase = dst * R_REL;

  int bnd = drs[segBase + (lane & 7)];
  const int a0    = __shfl(bnd, 0);
  const int total = __shfl(bnd, 7) - a0;

  int pk = 0;
  if (lane < total) pk = (int)esrc[a0 + lane];   // covers total<=64 (deg avg 12)

  const unsigned* colp = (const unsigned*)curA + lane;   // row stride = 64 uints

  int p = a0;
  int aPrev = a0;
#pragma unroll
  for (int r = 0; r < R_REL; ++r) {
    int br = __shfl(bnd, r + 1);
    float sx = 0.f, sy = 0.f;
    for (; p < br; ++p) {
      int idx = p - a0;
      int src = (idx < 64) ? __shfl(pk, idx) : (int)esrc[p];  // rare tail path
      unsigned v = colp[src * 64];
      sx += bf2f((unsigned short)(v & 0xFFFF));
      sy += bf2f((unsigned short)(v >> 16));
    }
    int c = br - aPrev;
    float sc = (c > 0) ? 1.0f / (float)c : 0.f;
    unsigned pck = (unsigned)f2bf(sx * sc) | ((unsigned)f2bf(sy * sc) << 16);
    *(unsigned*)(aggB + (size_t)dst * AGG_COLS + r * HID + lane * 2) = pck;
    aPrev = br;
  }
}

// ---------------------------------------------------------------- lin1 MFMA GEMM
// M=64 tile (grid 782), K=256 in 2 phases; x read fp32 + cast DURING staging.
// Output: b0 = bf16(t0*(x@w1+b1)) ONLY (no fp32 hidden).
__global__ __launch_bounds__(256) void gemm_lin1(
    const float* __restrict__ x,              // [N,256] fp32
    const unsigned short* __restrict__ BT,    // w1T [128,256] bf16
    const float* __restrict__ bias,
    const float* __restrict__ temp,
    unsigned short* __restrict__ b0out)       // [N,128] bf16
{
  __shared__ unsigned short Atile[64][136];    // 17.4 KB
  __shared__ unsigned short Btile[128][136];   // 34.8 KB
  const int tid  = threadIdx.x;
  const int row0 = blockIdx.x * 64;
  const int lane = tid & 63;
  const int wid  = tid >> 6;
  const int wrow = (wid & 1) * 32;
  const int wcol = (wid >> 1) * 64;
  const int l15  = lane & 15;
  const int quad = lane >> 4;

  floatx4 acc[2][4] = {};

  for (int k0 = 0; k0 < IN_C; k0 += 128) {
    // A: 64 rows x 128 k, cast fp32->bf16 in flight. 1024 chunks, 4/thread.
#pragma unroll
    for (int it = 0; it < 4; ++it) {
      int chunk = it * 256 + tid;
      int r = chunk >> 4, cc = (chunk & 15) << 3;
      int grow = row0 + r;
      uint4 va = make_uint4(0u, 0u, 0u, 0u);
      if (grow < N_NODES) {
        const float* xp = x + (size_t)grow * IN_C + k0 + cc;
        float4 f0 = *(const float4*)xp;
        float4 f1 = *(const float4*)(xp + 4);
        va.x = (unsigned)f2bf(f0.x) | ((unsigned)f2bf(f0.y) << 16);
        va.y = (unsigned)f2bf(f0.z) | ((unsigned)f2bf(f0.w) << 16);
        va.z = (unsigned)f2bf(f1.x) | ((unsigned)f2bf(f1.y) << 16);
        va.w = (unsigned)f2bf(f1.z) | ((unsigned)f2bf(f1.w) << 16);
      }
      *(uint4*)(&Atile[r][cc]) = va;
    }
    // B: 128 rows (out cols) x 128 k. 2048 chunks, 8/thread.
#pragma unroll
    for (int it = 0; it < 8; ++it) {
      int chunk = it * 256 + tid;
      int n = chunk >> 4, cc = (chunk & 15) << 3;
      *(uint4*)(&Btile[n][cc]) =
          *(const uint4*)(BT + (size_t)n * IN_C + k0 + cc);
    }
    __syncthreads();
#pragma unroll
    for (int ks = 0; ks < 4; ++ks) {
      int kc = ks * 32 + quad * 8;
      short8 af[2], bfr[4];
#pragma unroll
      for (int i = 0; i < 2; ++i)
        af[i] = *(const short8*)(&Atile[wrow + i * 16 + l15][kc]);
#pragma unroll
      for (int j = 0; j < 4; ++j)
        bfr[j] = *(const short8*)(&Btile[wcol + j * 16 + l15][kc]);
#pragma unroll
      for (int i = 0; i < 2; ++i)
#pragma unroll
        for (int j = 0; j < 4; ++j)
          acc[i][j] = __builtin_amdgcn_mfma_f32_16x16x32_bf16(
              af[i], bfr[j], acc[i][j], 0, 0, 0);
    }
    __syncthreads();
  }

  // epilogue: b0 = bf16(t0*(acc+bias)) via LDS transpose.
  float t0 = temp[0];
#pragma unroll
  for (int i = 0; i < 2; ++i) {
    int lrow0 = wrow + i * 16 + quad * 4;
#pragma unroll
    for (int j = 0; j < 4; ++j) {
      int gcol = wcol + j * 16 + l15;
      float bb = bias[gcol];
#pragma unroll
      for (int r = 0; r < 4; ++r)
        Atile[lrow0 + r][gcol] = f2bf(t0 * (acc[i][j][r] + bb));
    }
  }
  __syncthreads();
#pragma unroll
  for (int it = 0; it < 4; ++it) {
    int chunk = it * 256 + tid;
    int r = chunk >> 4, cc = (chunk & 15) << 3;
    int grow = row0 + r;
    if (grow < N_NODES)
      *(uint4*)(b0out + (size_t)grow * HID + cc) = *(const uint4*)(&Atile[r][cc]);
  }
}

// ---------------------------------------------------------------- layer MFMA GEMM
// M=32 tile (grid 1563), 4 waves of 16x64 (acc 1x4). A 8.7 KB + B 34.8 KB
// LDS-staged = 43.5 KB -> 3 blocks/CU. Epilogue writes ONLY bf16 c:
//   c = (l<2 ? relu : id)(acc+bias); bout = bf16(c). No hidden RMW.
__global__ __launch_bounds__(256) void gemm_layer(
    const unsigned short* __restrict__ curA,   // [N,128] bf16 (in, = b_l)
    const unsigned short* __restrict__ aggB,   // [N,896] bf16
    const unsigned short* __restrict__ BT,     // wcat2T [128][1024] bf16
    const float* __restrict__ bias,
    unsigned short* __restrict__ bout,         // [N,128] bf16 (out, = b_{l+1})
    int layer)
{
  __shared__ unsigned short Atile[32][136];    // 8.7 KB
  __shared__ unsigned short Btile[128][136];   // 34.8 KB
  const int tid  = threadIdx.x;
  const int row0 = blockIdx.x * 32;
  const int lane = tid & 63;
  const int wid  = tid >> 6;
  const int wrow = (wid & 1) * 16;
  const int wcol = (wid >> 1) * 64;
  const int l15  = lane & 15;
  const int quad = lane >> 4;

  floatx4 acc[4] = {};

  for (int p = 0; p < 8; ++p) {
    // B tile: 128 rows (out cols) x 128 k slice. 2048 chunks, 8/thread.
#pragma unroll
    for (int it = 0; it < 8; ++it) {
      int chunk = it * 256 + tid;
      int n = chunk >> 4, cc = (chunk & 15) << 3;
      *(uint4*)(&Btile[n][cc]) =
          *(const uint4*)(BT + (size_t)n * K_CAT + p * 128 + cc);
    }
    // A tile: 32 rows x 128 k. 512 chunks, 2/thread.
#pragma unroll
    for (int it = 0; it < 2; ++it) {
      int chunk = it * 256 + tid;
      int r = chunk >> 4, cc = (chunk & 15) << 3;
      int grow = row0 + r;
      uint4 va = make_uint4(0u, 0u, 0u, 0u);
      if (grow < N_NODES) {
        if (p == 0)
          va = *(const uint4*)(curA + (size_t)grow * HID + cc);
        else
          va = *(const uint4*)(aggB + (size_t)grow * AGG_COLS +
                               (p - 1) * 128 + cc);
      }
      *(uint4*)(&Atile[r][cc]) = va;
    }
    __syncthreads();
#pragma unroll
    for (int ks = 0; ks < 4; ++ks) {
      int kc = ks * 32 + quad * 8;
      short8 af = *(const short8*)(&Atile[wrow + l15][kc]);
      short8 bfr[4];
#pragma unroll
      for (int j = 0; j < 4; ++j)
        bfr[j] = *(const short8*)(&Btile[wcol + j * 16 + l15][kc]);
#pragma unroll
      for (int j = 0; j < 4; ++j)
        acc[j] = __builtin_amdgcn_mfma_f32_16x16x32_bf16(af, bfr[j], acc[j],
                                                         0, 0, 0);
    }
    __syncthreads();
  }

  // epilogue: bout = bf16((l<2?relu:id)(acc+bias)) via LDS transpose.
  const bool isLast = (layer == L_LAYERS - 1);
  {
    int lrow0 = wrow + quad * 4;
#pragma unroll
    for (int j = 0; j < 4; ++j) {
      int gcol = wcol + j * 16 + l15;
      float bb = bias[gcol];
#pragma unroll
      for (int r = 0; r < 4; ++r) {
        float c = acc[j][r] + bb;
        if (!isLast) c = fmaxf(c, 0.f);
        Atile[lrow0 + r][gcol] = f2bf(c);
      }
    }
  }
  __syncthreads();
#pragma unroll
  for (int it = 0; it < 2; ++it) {
    int chunk = it * 256 + tid;
    int r = chunk >> 4, cc = (chunk & 15) << 3;
    int grow = row0 + r;
    if (grow < N_NODES)
      *(uint4*)(bout + (size_t)grow * HID + cc) = *(const uint4*)(&Atile[r][cc]);
  }
}

// ---------------------------------------------------------------- final linear
// h[d] = b0 + temp[1]*b1 + temp[2]*b2 + temp[3]*b3 (bf16 terms), then lin2.
__global__ __launch_bounds__(256) void final_kernel(
    const unsigned short* __restrict__ b0, const unsigned short* __restrict__ b1,
    const unsigned short* __restrict__ b2v, const unsigned short* __restrict__ b3,
    const float* __restrict__ temp,
    const float* __restrict__ w2, const float* __restrict__ b2bias,
    float* __restrict__ out)
{
  int node = blockIdx.x * 4 + (threadIdx.x >> 6);
  int lane = threadIdx.x & 63;
  if (node >= N_NODES) return;
  float t1 = temp[1], t2 = temp[2], t3 = temp[3];
  size_t base = (size_t)node * 64 + lane;      // uint index: dims 2*lane,2*lane+1
  unsigned u0 = ((const unsigned*)b0)[base];
  unsigned u1 = ((const unsigned*)b1)[base];
  unsigned u2 = ((const unsigned*)b2v)[base];
  unsigned u3 = ((const unsigned*)b3)[base];
  float hx = bf2f((unsigned short)(u0 & 0xFFFF)) +
             t1 * bf2f((unsigned short)(u1 & 0xFFFF)) +
             t2 * bf2f((unsigned short)(u2 & 0xFFFF)) +
             t3 * bf2f((unsigned short)(u3 & 0xFFFF));
  float hy = bf2f((unsigned short)(u0 >> 16)) +
             t1 * bf2f((unsigned short)(u1 >> 16)) +
             t2 * bf2f((unsigned short)(u2 >> 16)) +
             t3 * bf2f((unsigned short)(u3 >> 16));
  int d0 = lane * 2, d1 = lane * 2 + 1;
  float a0 = hx * w2[d0 * 2 + 0] + hy * w2[d1 * 2 + 0];
  float a1 = hx * w2[d0 * 2 + 1] + hy * w2[d1 * 2 + 1];
#pragma unroll
  for (int off = 32; off > 0; off >>= 1) {
    a0 += __shfl_down(a0, off);
    a1 += __shfl_down(a1, off);
  }
  if (lane == 0) {
    out[node * 2 + 0] = a0 + b2bias[0];
    out[node * 2 + 1] = a1 + b2bias[1];
  }
}

// ---------------------------------------------------------------- launcher
extern "C" void kernel_launch(void* const* d_in, const int* in_sizes, int n_in,
                              void* d_out, int out_size, void* d_ws, size_t ws_size,
                              hipStream_t stream) {
  const float* x     = (const float*)d_in[0];
  const int*   ei    = (const int*)d_in[1];
  const int*   et    = (const int*)d_in[2];
  const float* temp  = (const float*)d_in[3];
  const float* w1    = (const float*)d_in[4];
  const float* b1    = (const float*)d_in[5];
  const float* w2    = (const float*)d_in[6];
  const float* b2    = (const float*)d_in[7];
  const float* comps = (const float*)d_in[8];
  const float* bases = (const float*)d_in[9];
  const float* roots = (const float*)d_in[10];
  const float* cbias = (const float*)d_in[11];

  char* ws = (char*)d_ws;
  size_t off = 0;
  auto take = [&](size_t bytes) {
    char* p = ws + off;
    off = (off + bytes + 255) & ~(size_t)255;
    return p;
  };
  unsigned short* wcat2T = (unsigned short*)take((size_t)L_LAYERS * 128 * K_CAT * 2); // 0.8 MB
  unsigned short* w1T    = (unsigned short*)take((size_t)HID * IN_C * 2);             // 64 KB
  int*   cntRel  = (int*)take((size_t)NR * 4);                  // 1.4 MB
  int*   tmpOffR = (int*)take((size_t)NR * 4);                  // 1.4 MB
  int*   blockSumsR = (int*)take((size_t)SCANR_BLOCKS * 4);
  int*   drs     = (int*)take((size_t)(NR + 1) * 4);            // 1.4 MB
  int*   cursorR = (int*)take((size_t)NR * 4);                  // 1.4 MB
  unsigned short* esrc = (unsigned short*)take((size_t)E_EDGES * 2); // 1.2 MB
  unsigned short* bl[L_LAYERS + 1];
  for (int i = 0; i <= L_LAYERS; ++i)
    bl[i] = (unsigned short*)take((size_t)N_NODES * HID * 2);   // 4 x 12.8 MB
  unsigned short* aggB = (unsigned short*)take((size_t)N_NODES * AGG_COLS * 2); // 89.6 MB

  hipMemsetAsync(cntRel, 0, (size_t)NR * 4, stream);
  hipMemsetAsync(cursorR, 0, (size_t)NR * 4, stream);

  hipLaunchKernelGGL(build_wcat2, dim3((L_LAYERS * 128 * K_CAT + 255) / 256),
                     dim3(256), 0, stream, comps, bases, roots, wcat2T);
  hipLaunchKernelGGL(cast_w1_kernel, dim3((HID * IN_C + 255) / 256), dim3(256),
                     0, stream, w1, w1T);
  hipLaunchKernelGGL(hist_kernel, dim3((E_EDGES + 255) / 256), dim3(256), 0,
                     stream, ei, et, cntRel);
  hipLaunchKernelGGL(scanA_kernel, dim3(SCANR_BLOCKS), dim3(256), 0, stream,
                     cntRel, tmpOffR, blockSumsR);
  hipLaunchKernelGGL(scanB_kernel, dim3(1), dim3(256), 0, stream, blockSumsR);
  hipLaunchKernelGGL(scanC_kernel, dim3(SCANR_BLOCKS), dim3(256), 0, stream,
                     tmpOffR, blockSumsR, drs);
  hipLaunchKernelGGL(place_kernel, dim3((E_EDGES + 255) / 256), dim3(256), 0,
                     stream, ei, et, drs, cursorR, esrc);

  const int rowBlocks64 = (N_NODES + 63) / 64;     // 782
  const int rowBlocks32 = (N_NODES + 31) / 32;     // 1563
  hipLaunchKernelGGL(gemm_lin1, dim3(rowBlocks64), dim3(256), 0, stream,
                     x, w1T, b1, temp, bl[0]);

  for (int l = 0; l < L_LAYERS; ++l) {
    hipLaunchKernelGGL(agg_reg_kernel, dim3((N_NODES + 3) / 4), dim3(256),
                       0, stream, bl[l], esrc, drs, aggB);
    hipLaunchKernelGGL(gemm_layer, dim3(rowBlocks32), dim3(256), 0, stream,
                       bl[l], aggB, wcat2T + (size_t)l * 128 * K_CAT,
                       cbias + (size_t)l * HID, bl[l + 1], l);
  }

  hipLaunchKernelGGL(final_kernel, dim3((N_NODES + 3) / 4), dim3(256), 0, stream,
                     bl[0], bl[1], bl[2], bl[3], temp, w2, b2, (float*)d_out);
}